// Round 2
// baseline (106.258 us; speedup 1.0000x reference)
//
#include <hip/hip_runtime.h>
#include <hip/hip_bf16.h>

// RNN_73048803770905: fused [B,T,200]x[200,64] projection + 128-step tanh RNN + sigmoid head.
// B=4096, T=128, D_IN=200, H=64. HBM-bound (419 MB x read, floor ~67us).
// Design: 256 blocks x 4 INDEPENDENT waves; each wave owns 4 batch rows end-to-end.
// Zero barriers. Projection A-tile = 4 rows x 4 timesteps. Recurrence fully in-wave,
// h exchanged via per-wave LDS; A-rows broadcast via (m&3) so all 64 lanes hold
// duplicated results -> per-g n-tile select -> 4 tanh/lane, 4 conflict-free b16 writes.
// x double-buffered in regs (pA/pB), 2-chunk prefetch distance.

#define TSEQ 128
#define DIN  200
#define HID  64
#define TC   4
#define NCH  (TSEQ/TC)

typedef short bf16x8 __attribute__((ext_vector_type(8)));
typedef float f32x4  __attribute__((ext_vector_type(4)));

__device__ __forceinline__ short f2bf(float f) {
  __hip_bfloat16 h = __float2bfloat16(f);
  return __builtin_bit_cast(short, h);
}
__device__ __forceinline__ bf16x8 cvt8(f32x4 a, f32x4 b) {
  bf16x8 r;
#pragma unroll
  for (int i = 0; i < 4; ++i) { r[i] = f2bf(a[i]); r[4 + i] = f2bf(b[i]); }
  return r;
}
// tanh(x) = 1 - 2/(1 + 2^(x*2/ln2)); v_exp handles inf/0 so no clamp needed.
__device__ __forceinline__ float tanh_fast(float x) {
  float e = exp2f(x * 2.885390081777927f);
  float r = __builtin_amdgcn_rcpf(1.f + e);
  return __builtin_fmaf(-2.f, r, 1.f);
}

__global__ __launch_bounds__(256, 1) void rnn_fused(
    const float* __restrict__ x,   const float* __restrict__ Wih,
    const float* __restrict__ Whh, const float* __restrict__ bih,
    const float* __restrict__ bhh, const float* __restrict__ Wout,
    const float* __restrict__ bout, float* __restrict__ out)
{
  // per-wave regions, no cross-wave sharing:
  __shared__ float          xps[4][TC][HID][4];   // [wave][tl][h][rb] f32, 16 KB
  __shared__ unsigned short hb [4][4][HID];       // [wave][rb][h] bf16 bits, 2 KB

  const int tid  = threadIdx.x;
  const int w    = tid >> 6;
  const int lane = tid & 63;
  const int m    = lane & 15;      // MFMA row/col-in-tile
  const int g    = lane >> 4;      // 16-lane group 0..3
  const int bw   = blockIdx.x * 16 + w * 4;   // this wave's first batch row

  // A row = rb*4 + tl  (rb = m>>2 batch row, tl = m&3 timestep within chunk)
  const float* xrow = x + ((size_t)(bw + (m >> 2)) * TSEQ + (m & 3)) * DIN;

  f32x4 pA[7][2], pB[7][2];
  auto LOADC = [&](f32x4 (&P)[7][2], int c) {
    const float* p = xrow + (size_t)c * (TC * DIN);
#pragma unroll
    for (int ks = 0; ks < 7; ++ks) {
      const int d = ks * 32 + g * 8;
      if (d + 8 <= DIN) {
        P[ks][0] = *reinterpret_cast<const f32x4*>(p + d);
        P[ks][1] = *reinterpret_cast<const f32x4*>(p + d + 4);
      } else {
        P[ks][0] = (f32x4)0.f; P[ks][1] = (f32x4)0.f;   // d=200..223 tail: keep zero
      }
    }
  };
  LOADC(pA, 0);
  LOADC(pB, 1);

  // ---- weights into registers (L2-resident, read once per wave) ----
  bf16x8 wihf[4][7];   // B[k=d][n=h]: lane h = nt*16+m, d = ks*32+g*8+j
#pragma unroll
  for (int nt = 0; nt < 4; ++nt) {
    const float* wr = Wih + (size_t)(nt * 16 + m) * DIN;
#pragma unroll
    for (int ks = 0; ks < 7; ++ks) {
      const int d = ks * 32 + g * 8;
      if (d + 8 <= DIN)
        wihf[nt][ks] = cvt8(*reinterpret_cast<const f32x4*>(wr + d),
                            *reinterpret_cast<const f32x4*>(wr + d + 4));
      else
        wihf[nt][ks] = (bf16x8)0;
    }
  }
  bf16x8 whhf[4][2];   // B[k][n=h]: lane h = nt*16+m, k = hf*32+g*8+j
#pragma unroll
  for (int nt = 0; nt < 4; ++nt)
#pragma unroll
    for (int hf = 0; hf < 2; ++hf) {
      const float* wr = Whh + (size_t)(nt * 16 + m) * HID + hf * 32 + g * 8;
      whhf[nt][hf] = cvt8(*reinterpret_cast<const f32x4*>(wr),
                          *reinterpret_cast<const f32x4*>(wr + 4));
    }
  float biasv[4];
#pragma unroll
  for (int nt = 0; nt < 4; ++nt) biasv[nt] = bih[nt * 16 + m] + bhh[nt * 16 + m];
  const float woutv = Wout[g * 16 + m];
  const float bout0 = bout[0];

  // h_{-1} = 0
  reinterpret_cast<unsigned int*>(&hb[w][0][0])[lane]      = 0u;
  reinterpret_cast<unsigned int*>(&hb[w][0][0])[lane + 64] = 0u;

  float vf[4];   // final-step h (f32) for the epilogue: vf[r] = h[r][g*16+m]

  auto BODY = [&](f32x4 (&P)[7][2], int c) {
    // consume chunk c (vmcnt wait lands here), then refill same buffer with c+2
    bf16x8 afr[7];
#pragma unroll
    for (int ks = 0; ks < 7; ++ks) afr[ks] = cvt8(P[ks][0], P[ks][1]);
    if (c + 2 < NCH) LOADC(P, c + 2);

    // projection: xp = x * Wih^T + (b_ih + b_hh), A rows = (rb,tl)
    f32x4 acc[4];
#pragma unroll
    for (int nt = 0; nt < 4; ++nt) acc[nt] = (f32x4)(biasv[nt]);
#pragma unroll
    for (int ks = 0; ks < 7; ++ks)
#pragma unroll
      for (int nt = 0; nt < 4; ++nt)
        acc[nt] = __builtin_amdgcn_mfma_f32_16x16x32_bf16(afr[ks], wihf[nt][ks], acc[nt], 0, 0, 0);

    // D row = g*4+rr -> rb = g, tl = rr.  Write [tl][h][rb]: banks (4l+g)%32, ~conflict-free.
#pragma unroll
    for (int nt = 0; nt < 4; ++nt)
#pragma unroll
      for (int rr = 0; rr < 4; ++rr)
        xps[w][rr][nt * 16 + m][g] = acc[nt][rr];

    // recurrence: 4 sequential steps, fully in-wave (compiler lgkmcnt handles RAW)
#pragma unroll
    for (int tl = 0; tl < TC; ++tl) {
      f32x4 racc[4];
#pragma unroll
      for (int nt = 0; nt < 4; ++nt)   // C rows r = batch r; all g broadcast same addr
        racc[nt] = *reinterpret_cast<const f32x4*>(&xps[w][tl][nt * 16 + m][0]);
      // A rows broadcast: row m -> h[m&3], so D rows 4g+r duplicate batch r across g
      bf16x8 ha0 = *reinterpret_cast<const bf16x8*>(&hb[w][m & 3][g * 8]);
      bf16x8 ha1 = *reinterpret_cast<const bf16x8*>(&hb[w][m & 3][32 + g * 8]);
#pragma unroll
      for (int nt = 0; nt < 4; ++nt) {
        racc[nt] = __builtin_amdgcn_mfma_f32_16x16x32_bf16(ha0, whhf[nt][0], racc[nt], 0, 0, 0);
        racc[nt] = __builtin_amdgcn_mfma_f32_16x16x32_bf16(ha1, whhf[nt][1], racc[nt], 0, 0, 0);
      }
      // each g-group owns n-tile nt=g: select, tanh 4 values, write h[r][g*16+m]
#pragma unroll
      for (int r = 0; r < 4; ++r) {
        float v = (g == 0) ? racc[0][r] : (g == 1) ? racc[1][r]
                 : (g == 2) ? racc[2][r] : racc[3][r];
        v = tanh_fast(v);
        vf[r] = v;
        hb[w][r][g * 16 + m] = (unsigned short)f2bf(v);   // banks g*8+m/2: conflict-free
      }
    }
  };

  for (int c = 0; c < NCH; c += 2) { BODY(pA, c); BODY(pB, c + 1); }

  // ---- epilogue: out[bw+r] = sigmoid(h_last[r] . Wout + bout) ----
  f32x4 s;
#pragma unroll
  for (int r = 0; r < 4; ++r) s[r] = vf[r] * woutv;
#pragma unroll
  for (int mask = 1; mask < 64; mask <<= 1) {
#pragma unroll
    for (int r = 0; r < 4; ++r) s[r] += __shfl_xor(s[r], mask, 64);
  }
  if (lane == 0) {
    f32x4 o;
#pragma unroll
    for (int r = 0; r < 4; ++r) {
      const float z = s[r] + bout0;
      o[r] = __builtin_amdgcn_rcpf(1.f + exp2f(-z * 1.4426950408889634f));
    }
    *reinterpret_cast<f32x4*>(out + bw) = o;
  }
}

extern "C" void kernel_launch(void* const* d_in, const int* in_sizes, int n_in,
                              void* d_out, int out_size, void* d_ws, size_t ws_size,
                              hipStream_t stream) {
  const float* x    = (const float*)d_in[0];
  const float* Wih  = (const float*)d_in[1];
  const float* Whh  = (const float*)d_in[2];
  const float* bih  = (const float*)d_in[3];
  const float* bhh  = (const float*)d_in[4];
  const float* Wout = (const float*)d_in[5];
  const float* bout = (const float*)d_in[6];
  float* out = (float*)d_out;

  const int B = in_sizes[0] / (TSEQ * DIN);   // 4096
  rnn_fused<<<dim3(B / 16), dim3(256), 0, stream>>>(x, Wih, Whh, bih, bhh, Wout, bout, out);
}